// Round 1
// baseline (253.894 us; speedup 1.0000x reference)
//
#include <hip/hip_runtime.h>
#include <math.h>

// QuadraticNetCholesky fused kernel.
// Key algebraic simplification: y = x^T (L L^T) x = ||L^T x||^2, so we never
// build L/A. v_j = sum_{i>=j} x_i * c[i(i+1)/2 + j]; y = sum_j v_j^2.

constexpr int NI = 24;    // input size
constexpr int H1 = 128;
constexpr int H2 = 32;

__device__ __forceinline__ float elu_f(float v) {
    // jax.nn.elu (alpha=1): x>0 ? x : expm1(x)
    return v > 0.0f ? v : expm1f(v);
}

__device__ __forceinline__ float softplus_f(float v) {
    // stable log1p(exp(v))
    return fmaxf(v, 0.0f) + log1pf(expf(-fabsf(v)));
}

__global__ __launch_bounds__(256) void qnet_fused(
    const float* __restrict__ x,
    const float* __restrict__ W1, const float* __restrict__ b1,
    const float* __restrict__ W2, const float* __restrict__ b2,
    const float* __restrict__ W3, const float* __restrict__ b3,
    float* __restrict__ y, int B)
{
    // Per-thread x row staged in LDS for runtime indexing in stage 3.
    // Stride 25 (coprime with 32 banks) -> conflict-free; each thread only
    // touches its own row, so no __syncthreads needed.
    __shared__ float xs[256][NI + 1];
    const int tid = threadIdx.x;
    const int s = blockIdx.x * 256 + tid;
    if (s >= B) return;

    // ---- load x (24 floats = 6x float4, 96B-aligned per sample) ----
    float xr[NI];
    {
        const float4* xp4 = reinterpret_cast<const float4*>(x + (size_t)s * NI);
        #pragma unroll
        for (int q = 0; q < NI / 4; ++q) {
            float4 v = xp4[q];
            xr[4*q+0] = v.x; xr[4*q+1] = v.y; xr[4*q+2] = v.z; xr[4*q+3] = v.w;
        }
    }
    #pragma unroll
    for (int k = 0; k < NI; ++k) xs[tid][k] = xr[k];

    // ---- stage 1+2 fused: h2 = W2 @ elu(W1 @ x + b1) + b2, chunked by 8 ----
    float h2a[H2];
    #pragma unroll
    for (int r = 0; r < H2; ++r) h2a[r] = b2[r];

    for (int c0 = 0; c0 < H1; c0 += 8) {   // runtime loop: keeps code small,
        float h1c[8];                      // W-addresses stay wave-uniform -> s_load
        #pragma unroll
        for (int r = 0; r < 8; ++r) {
            const float* w = W1 + (c0 + r) * NI;
            float a0 = 0.f, a1 = 0.f, a2 = 0.f, a3 = 0.f;
            #pragma unroll
            for (int k = 0; k < NI; k += 4) {
                a0 = fmaf(xr[k+0], w[k+0], a0);
                a1 = fmaf(xr[k+1], w[k+1], a1);
                a2 = fmaf(xr[k+2], w[k+2], a2);
                a3 = fmaf(xr[k+3], w[k+3], a3);
            }
            h1c[r] = elu_f((a0 + a1) + (a2 + a3) + b1[c0 + r]);
        }
        #pragma unroll
        for (int r = 0; r < H2; ++r) {
            float a = h2a[r];
            const float* w = W2 + r * H1 + c0;
            #pragma unroll
            for (int k = 0; k < 8; ++k) a = fmaf(h1c[k], w[k], a);
            h2a[r] = a;
        }
    }
    #pragma unroll
    for (int r = 0; r < H2; ++r) h2a[r] = elu_f(h2a[r]);

    // ---- stage 3: y = sum_j ( sum_{i>=j} x_i * softplus(W3[t].h2 + b3[t]) )^2
    float acc_y = 0.f;
    for (int j = 0; j < NI; ++j) {
        float v = 0.f;
        for (int i = j; i < NI; ++i) {
            const int t = (i * (i + 1)) / 2 + j;   // row-major tril index
            const float* w = W3 + t * H2;          // wave-uniform -> s_load
            float a0 = 0.f, a1 = 0.f, a2 = 0.f, a3 = 0.f;
            #pragma unroll
            for (int k = 0; k < H2; k += 4) {
                a0 = fmaf(h2a[k+0], w[k+0], a0);
                a1 = fmaf(h2a[k+1], w[k+1], a1);
                a2 = fmaf(h2a[k+2], w[k+2], a2);
                a3 = fmaf(h2a[k+3], w[k+3], a3);
            }
            float cv = softplus_f((a0 + a1) + (a2 + a3) + b3[t]);
            v = fmaf(xs[tid][i], cv, v);
        }
        acc_y = fmaf(v, v, acc_y);
    }
    y[s] = acc_y;
}

extern "C" void kernel_launch(void* const* d_in, const int* in_sizes, int n_in,
                              void* d_out, int out_size, void* d_ws, size_t ws_size,
                              hipStream_t stream) {
    const float* x  = (const float*)d_in[0];
    const float* W1 = (const float*)d_in[1];
    const float* b1 = (const float*)d_in[2];
    const float* W2 = (const float*)d_in[3];
    const float* b2 = (const float*)d_in[4];
    const float* W3 = (const float*)d_in[5];
    const float* b3 = (const float*)d_in[6];
    float* y = (float*)d_out;

    const int B = in_sizes[0] / NI;   // 131072
    dim3 grid((B + 255) / 256);
    qnet_fused<<<grid, dim3(256), 0, stream>>>(x, W1, b1, W2, b2, W3, b3, y, B);
}

// Round 2
// 154.571 us; speedup vs baseline: 1.6426x; 1.6426x over previous
//
#include <hip/hip_runtime.h>
#include <math.h>

// QuadraticNetCholesky fused kernel, round 2.
// y = x^T (L L^T) x = ||L^T x||^2 ; v_j = sum_{i>=j} x_i * c[i(i+1)/2 + j].
// R2: replace libm expf/log1pf/expm1f with hardware v_exp_f32/v_log_f32
// (__expf/__logf). Accuracy cost ~1e-6 rel, threshold headroom is ~10x.

constexpr int NI = 24;    // input size
constexpr int H1 = 128;
constexpr int H2 = 32;

__device__ __forceinline__ float elu_f(float v) {
    // alpha=1 ELU; exp(v)-1 abs err ~1e-7 for v<=0 (vs expm1) — fine here.
    return v > 0.0f ? v : __expf(v) - 1.0f;
}

__device__ __forceinline__ float softplus_f(float v) {
    // stable: max(v,0) + log(1+exp(-|v|)); hw exp/log. exp underflow -> log(1)=0.
    return fmaxf(v, 0.0f) + __logf(1.0f + __expf(-fabsf(v)));
}

__global__ __launch_bounds__(256) void qnet_fused(
    const float* __restrict__ x,
    const float* __restrict__ W1, const float* __restrict__ b1,
    const float* __restrict__ W2, const float* __restrict__ b2,
    const float* __restrict__ W3, const float* __restrict__ b3,
    float* __restrict__ y, int B)
{
    // Per-thread x row staged in LDS for runtime indexing in stage 3.
    // Stride 25 (coprime with 32 banks) -> conflict-free (verified: 0 conflicts).
    __shared__ float xs[256][NI + 1];
    const int tid = threadIdx.x;
    const int s = blockIdx.x * 256 + tid;
    if (s >= B) return;

    // ---- load x (24 floats = 6x float4) ----
    float xr[NI];
    {
        const float4* xp4 = reinterpret_cast<const float4*>(x + (size_t)s * NI);
        #pragma unroll
        for (int q = 0; q < NI / 4; ++q) {
            float4 v = xp4[q];
            xr[4*q+0] = v.x; xr[4*q+1] = v.y; xr[4*q+2] = v.z; xr[4*q+3] = v.w;
        }
    }
    #pragma unroll
    for (int k = 0; k < NI; ++k) xs[tid][k] = xr[k];

    // ---- stage 1+2 fused: h2 = W2 @ elu(W1 @ x + b1) + b2, chunked by 8 ----
    float h2a[H2];
    #pragma unroll
    for (int r = 0; r < H2; ++r) h2a[r] = b2[r];

    for (int c0 = 0; c0 < H1; c0 += 8) {   // W addresses wave-uniform -> s_load
        float h1c[8];
        #pragma unroll
        for (int r = 0; r < 8; ++r) {
            const float* w = W1 + (c0 + r) * NI;
            float a0 = 0.f, a1 = 0.f, a2 = 0.f, a3 = 0.f;
            #pragma unroll
            for (int k = 0; k < NI; k += 4) {
                a0 = fmaf(xr[k+0], w[k+0], a0);
                a1 = fmaf(xr[k+1], w[k+1], a1);
                a2 = fmaf(xr[k+2], w[k+2], a2);
                a3 = fmaf(xr[k+3], w[k+3], a3);
            }
            h1c[r] = elu_f((a0 + a1) + (a2 + a3) + b1[c0 + r]);
        }
        #pragma unroll
        for (int r = 0; r < H2; ++r) {
            float a = h2a[r];
            const float* w = W2 + r * H1 + c0;
            #pragma unroll
            for (int k = 0; k < 8; ++k) a = fmaf(h1c[k], w[k], a);
            h2a[r] = a;
        }
    }
    #pragma unroll
    for (int r = 0; r < H2; ++r) h2a[r] = elu_f(h2a[r]);

    // ---- stage 3: y = sum_j ( sum_{i>=j} x_i * softplus(W3[t].h2 + b3[t]) )^2
    float acc_y = 0.f;
    for (int j = 0; j < NI; ++j) {
        float v = 0.f;
        for (int i = j; i < NI; ++i) {
            const int t = (i * (i + 1)) / 2 + j;   // row-major tril index
            const float* w = W3 + t * H2;          // wave-uniform -> s_load
            float a0 = 0.f, a1 = 0.f, a2 = 0.f, a3 = 0.f;
            #pragma unroll
            for (int k = 0; k < H2; k += 4) {
                a0 = fmaf(h2a[k+0], w[k+0], a0);
                a1 = fmaf(h2a[k+1], w[k+1], a1);
                a2 = fmaf(h2a[k+2], w[k+2], a2);
                a3 = fmaf(h2a[k+3], w[k+3], a3);
            }
            float cv = softplus_f((a0 + a1) + (a2 + a3) + b3[t]);
            v = fmaf(xs[tid][i], cv, v);
        }
        acc_y = fmaf(v, v, acc_y);
    }
    y[s] = acc_y;
}

extern "C" void kernel_launch(void* const* d_in, const int* in_sizes, int n_in,
                              void* d_out, int out_size, void* d_ws, size_t ws_size,
                              hipStream_t stream) {
    const float* x  = (const float*)d_in[0];
    const float* W1 = (const float*)d_in[1];
    const float* b1 = (const float*)d_in[2];
    const float* W2 = (const float*)d_in[3];
    const float* b2 = (const float*)d_in[4];
    const float* W3 = (const float*)d_in[5];
    const float* b3 = (const float*)d_in[6];
    float* y = (float*)d_out;

    const int B = in_sizes[0] / NI;   // 131072
    dim3 grid((B + 255) / 256);
    qnet_fused<<<grid, dim3(256), 0, stream>>>(x, W1, b1, W2, b2, W3, b3, y, B);
}

// Round 3
// 141.547 us; speedup vs baseline: 1.7937x; 1.0920x over previous
//
#include <hip/hip_runtime.h>
#include <math.h>

// QuadraticNetCholesky fused kernel, round 3.
// y = x^T (L L^T) x = ||L^T x||^2 ; v_j = sum_{i>=j} x_i * c[i(i+1)/2 + j].
// R3: 2 threads per sample to double resident waves (was grid-limited at
// 2 waves/SIMD, latency-bound: VALUBusy 35%, both pipes idle).
//   half0 (waves 0-1): h1 rows 0..63,  stage-3 odd j  (144 inner iters)
//   half1 (waves 2-3): h1 rows 64..127, stage-3 even j (156 inner iters)
// `half` is readfirstlane'd so W1/W2/W3 addresses stay wave-uniform -> s_load.

constexpr int NI  = 24;
constexpr int H1  = 128;
constexpr int H2  = 32;
constexpr int SPB = 128;   // samples per block (256 threads)

__device__ __forceinline__ float elu_f(float v) {
    return v > 0.0f ? v : __expf(v) - 1.0f;
}
__device__ __forceinline__ float softplus_f(float v) {
    return fmaxf(v, 0.0f) + __logf(1.0f + __expf(-fabsf(v)));
}

__global__ __launch_bounds__(256, 4) void qnet_fused(
    const float* __restrict__ x,
    const float* __restrict__ W1, const float* __restrict__ b1,
    const float* __restrict__ W2, const float* __restrict__ b2,
    const float* __restrict__ W3, const float* __restrict__ b3,
    float* __restrict__ y, int B)
{
    __shared__ float xs[SPB][NI + 1];   // stride 25: conflict-free
    __shared__ float h2x[SPB][H2 + 1];  // stride 33: conflict-free
    __shared__ float yb[SPB];

    const int tid  = threadIdx.x;
    const int sid  = tid & (SPB - 1);
    // wave-uniform (waves 0-1 -> 0, waves 2-3 -> 1); force to SGPR so
    // weight addresses derived from it stay scalar.
    const int half = __builtin_amdgcn_readfirstlane(tid >> 7);
    const int s    = blockIdx.x * SPB + sid;   // B == grid*SPB exactly

    // ---- load x (both halves keep it in regs; half0 stages to LDS) ----
    float xr[NI];
    {
        const float4* xp4 = reinterpret_cast<const float4*>(x + (size_t)s * NI);
        #pragma unroll
        for (int q = 0; q < NI / 4; ++q) {
            float4 v = xp4[q];
            xr[4*q+0] = v.x; xr[4*q+1] = v.y; xr[4*q+2] = v.z; xr[4*q+3] = v.w;
        }
    }
    if (half == 0) {
        #pragma unroll
        for (int k = 0; k < NI; ++k) xs[sid][k] = xr[k];
    }

    // ---- stage 1+2 (my 64 h1 rows), chunked by 8, partial h2 ----
    float h2p[H2];
    #pragma unroll
    for (int r = 0; r < H2; ++r) h2p[r] = 0.0f;

    const int rbase = half * (H1 / 2);
    for (int c0 = 0; c0 < H1 / 2; c0 += 8) {
        float h1c[8];
        #pragma unroll
        for (int r = 0; r < 8; ++r) {
            const float* w = W1 + (rbase + c0 + r) * NI;
            float a0 = 0.f, a1 = 0.f, a2 = 0.f, a3 = 0.f;
            #pragma unroll
            for (int k = 0; k < NI; k += 4) {
                a0 = fmaf(xr[k+0], w[k+0], a0);
                a1 = fmaf(xr[k+1], w[k+1], a1);
                a2 = fmaf(xr[k+2], w[k+2], a2);
                a3 = fmaf(xr[k+3], w[k+3], a3);
            }
            h1c[r] = elu_f((a0 + a1) + (a2 + a3) + b1[rbase + c0 + r]);
        }
        #pragma unroll
        for (int r = 0; r < H2; ++r) {
            float a = h2p[r];
            const float* w = W2 + r * H1 + rbase + c0;
            #pragma unroll
            for (int k = 0; k < 8; ++k) a = fmaf(h1c[k], w[k], a);
            h2p[r] = a;
        }
    }

    // ---- exchange partials: half1 -> LDS, half0 completes, writes full ----
    float h2a[H2];
    if (half == 1) {
        #pragma unroll
        for (int r = 0; r < H2; ++r) h2x[sid][r] = h2p[r];
    }
    __syncthreads();
    if (half == 0) {
        #pragma unroll
        for (int r = 0; r < H2; ++r) {
            h2a[r] = elu_f(h2p[r] + h2x[sid][r] + b2[r]);
            h2x[sid][r] = h2a[r];
        }
    }
    __syncthreads();
    if (half == 1) {
        #pragma unroll
        for (int r = 0; r < H2; ++r) h2a[r] = h2x[sid][r];
    }

    // ---- stage 3: y = sum_j v_j^2, j-parity split across halves ----
    // half0 -> odd j (sum 144 iters), half1 -> even j (156) — half0 also did
    // the h2 completion work, so it gets the lighter parity.
    const int j0 = half ? 0 : 1;
    float acc_y = 0.f;
    for (int jj = 0; jj < NI / 2; ++jj) {
        const int j = 2 * jj + j0;            // wave-uniform
        float v = 0.f;
        for (int i = j; i < NI; ++i) {
            const int t = (i * (i + 1)) / 2 + j;
            const float* w = W3 + t * H2;     // wave-uniform -> s_load
            float a0 = 0.f, a1 = 0.f, a2 = 0.f, a3 = 0.f;
            #pragma unroll
            for (int k = 0; k < H2; k += 4) {
                a0 = fmaf(h2a[k+0], w[k+0], a0);
                a1 = fmaf(h2a[k+1], w[k+1], a1);
                a2 = fmaf(h2a[k+2], w[k+2], a2);
                a3 = fmaf(h2a[k+3], w[k+3], a3);
            }
            float cv = softplus_f((a0 + a1) + (a2 + a3) + b3[t]);
            v = fmaf(xs[sid][i], cv, v);
        }
        acc_y = fmaf(v, v, acc_y);
    }

    // ---- combine the two halves' partial y ----
    if (half == 1) yb[sid] = acc_y;
    __syncthreads();
    if (half == 0) y[s] = acc_y + yb[sid];
}

extern "C" void kernel_launch(void* const* d_in, const int* in_sizes, int n_in,
                              void* d_out, int out_size, void* d_ws, size_t ws_size,
                              hipStream_t stream) {
    const float* x  = (const float*)d_in[0];
    const float* W1 = (const float*)d_in[1];
    const float* b1 = (const float*)d_in[2];
    const float* W2 = (const float*)d_in[3];
    const float* b2 = (const float*)d_in[4];
    const float* W3 = (const float*)d_in[5];
    const float* b3 = (const float*)d_in[6];
    float* y = (float*)d_out;

    const int B = in_sizes[0] / NI;   // 131072
    dim3 grid((B + SPB - 1) / SPB);
    qnet_fused<<<grid, dim3(256), 0, stream>>>(x, W1, b1, W2, b2, W3, b3, y, B);
}

// Round 4
// 79.578 us; speedup vs baseline: 3.1905x; 1.7787x over previous
//
#include <hip/hip_runtime.h>
#include <hip/hip_bf16.h>
#include <math.h>

// QuadraticNetCholesky fused kernel, round 4.
// y = x^T (L L^T) x = ||L^T x||^2 ; v_j = sum_{i>=j} x_i * c[i(i+1)/2 + j].
// R4: stage-3 matmul (9600 of ~17k FMAs/sample) moved to MFMA
// (mfma_f32_16x16x32_bf16, K=32 == H2 exactly). W3 pre-converted to bf16
// [304x32] in d_ws. c routed via chunked LDS (5 chunks x 64 cols, stride 65).
// v-accumulation fully compile-time unrolled (t(i,j) and chunk base constexpr)
// -> x stays in registers, no xs LDS, v[12] statically indexed.

constexpr int NI  = 24;
constexpr int H1  = 128;
constexpr int H2  = 32;
constexpr int SPB = 128;     // samples per block (256 threads, 4 waves)
constexpr int NT_TOT = 19;   // ceil(300/16) N-tiles
constexpr int W3R = 304;     // padded tril rows in d_ws

typedef __attribute__((ext_vector_type(8))) short bf16x8;
typedef __attribute__((ext_vector_type(4))) float f32x4;

__device__ __forceinline__ float elu_f(float v) {
    return v > 0.0f ? v : __expf(v) - 1.0f;
}
__device__ __forceinline__ float softplus_f(float v) {
    return fmaxf(v, 0.0f) + __logf(1.0f + __expf(-fabsf(v)));
}
__device__ __forceinline__ unsigned short f2bf(float f) {
    return __builtin_bit_cast(unsigned short, __float2bfloat16(f));
}

// ---- prologue: W3 [300][32] fp32 -> [304][32] bf16 in d_ws (rows 300.. = 0)
__global__ void w3cvt(const float* __restrict__ W3, unsigned short* __restrict__ w3b) {
    int idx = blockIdx.x * 256 + threadIdx.x;
    if (idx < W3R * H2) {
        int t = idx >> 5;
        w3b[idx] = f2bf(t < 300 ? W3[idx] : 0.0f);
    }
}

// compile-time-pruned v accumulation: only t in [C0, C0+64) emitted
template<int J0, int C0>
__device__ __forceinline__ void vaccum(const float xr[NI], float v[12],
                                       const float* __restrict__ crow) {
    #pragma unroll
    for (int q = 0; q < 12; ++q) {
        const int j = 2 * q + J0;
        #pragma unroll
        for (int i = j; i < NI; ++i) {
            const int t = i * (i + 1) / 2 + j;      // constexpr tril index
            if (t >= C0 && t < C0 + 64)
                v[q] = fmaf(xr[i], crow[t - C0], v[q]);
        }
    }
}

template<int CH>
__device__ __forceinline__ void chunk_body(
    int wid, int lane, int sid, int half,
    const unsigned short* __restrict__ w3b, const float* __restrict__ b3,
    const float xr[NI], float v[12],
    float (*c_buf)[65], const unsigned short (*h2l)[40])
{
    constexpr int C0 = CH * 64;
    const int nt = CH * 4 + wid;          // wave-uniform N-tile
    const int lr = lane & 15, lq = lane >> 4;
    if (nt < NT_TOT) {
        const int t = nt * 16 + lr;
        // B-frag: 8 contiguous bf16 along K from W3bf row t (16B aligned)
        bf16x8 bfrag = *reinterpret_cast<const bf16x8*>(w3b + t * H2 + lq * 8);
        const float bias = b3[t < 300 ? t : 299];   // clamp keeps pad in-bounds
        #pragma unroll
        for (int st = 0; st < SPB / 16; ++st) {
            // A-frag: row = sample (lane&15), k = 8*(lane>>4)+j contiguous
            bf16x8 afrag = *reinterpret_cast<const bf16x8*>(&h2l[st * 16 + lr][lq * 8]);
            f32x4 acc = {0.f, 0.f, 0.f, 0.f};
            acc = __builtin_amdgcn_mfma_f32_16x16x32_bf16(afrag, bfrag, acc, 0, 0, 0);
            // C-frag: col = lane&15 (=tril), row = 4*(lane>>4)+reg (=sample)
            #pragma unroll
            for (int r = 0; r < 4; ++r) {
                c_buf[st * 16 + lq * 4 + r][(nt & 3) * 16 + lr] =
                    softplus_f(acc[r] + bias);
            }
        }
    }
    __syncthreads();
    if (half == 0) vaccum<1, C0>(xr, v, c_buf[sid]);   // odd j
    else           vaccum<0, C0>(xr, v, c_buf[sid]);   // even j
    __syncthreads();
}

__global__ __launch_bounds__(256, 3) void qnet_fused(
    const float* __restrict__ x,
    const float* __restrict__ W1, const float* __restrict__ b1,
    const float* __restrict__ W2, const float* __restrict__ b2,
    const unsigned short* __restrict__ w3b, const float* __restrict__ b3,
    float* __restrict__ y, int B)
{
    __shared__ __align__(16) float c_buf[SPB][65];          // 33.3 KB (also h2 exchange)
    __shared__ __align__(16) unsigned short h2l[SPB][40];   // 10 KB bf16 h2, padded row
    __shared__ float yb[SPB];

    const int tid  = threadIdx.x;
    const int sid  = tid & (SPB - 1);
    const int lane = tid & 63;
    const int half = __builtin_amdgcn_readfirstlane(tid >> 7);
    const int wid  = __builtin_amdgcn_readfirstlane(tid >> 6);
    const int s    = blockIdx.x * SPB + sid;   // B % SPB == 0

    // ---- load x into registers (stays there the whole kernel) ----
    float xr[NI];
    {
        const float4* xp4 = reinterpret_cast<const float4*>(x + (size_t)s * NI);
        #pragma unroll
        for (int q = 0; q < NI / 4; ++q) {
            float4 t4 = xp4[q];
            xr[4*q+0] = t4.x; xr[4*q+1] = t4.y; xr[4*q+2] = t4.z; xr[4*q+3] = t4.w;
        }
    }

    // ---- stage 1+2 partial (my 64 h1 rows), fp32 VALU ----
    float h2p[H2];
    #pragma unroll
    for (int r = 0; r < H2; ++r) h2p[r] = 0.f;
    const int rbase = half * (H1 / 2);
    for (int c0 = 0; c0 < H1 / 2; c0 += 8) {
        float h1c[8];
        #pragma unroll
        for (int r = 0; r < 8; ++r) {
            const float* w = W1 + (rbase + c0 + r) * NI;
            float a0 = 0.f, a1 = 0.f, a2 = 0.f, a3 = 0.f;
            #pragma unroll
            for (int k = 0; k < NI; k += 4) {
                a0 = fmaf(xr[k+0], w[k+0], a0);
                a1 = fmaf(xr[k+1], w[k+1], a1);
                a2 = fmaf(xr[k+2], w[k+2], a2);
                a3 = fmaf(xr[k+3], w[k+3], a3);
            }
            h1c[r] = elu_f((a0 + a1) + (a2 + a3) + b1[rbase + c0 + r]);
        }
        #pragma unroll
        for (int r = 0; r < H2; ++r) {
            float a = h2p[r];
            const float* w = W2 + r * H1 + rbase + c0;
            #pragma unroll
            for (int k = 0; k < 8; ++k) a = fmaf(h1c[k], w[k], a);
            h2p[r] = a;
        }
    }

    // ---- exchange partials via c_buf; half0 completes h2, stores bf16 ----
    if (half == 1) {
        #pragma unroll
        for (int r = 0; r < H2; ++r) c_buf[sid][r] = h2p[r];
    }
    __syncthreads();
    if (half == 0) {
        unsigned int pk[H2 / 2];
        #pragma unroll
        for (int r = 0; r < H2; r += 2) {
            float e0 = elu_f(h2p[r]   + c_buf[sid][r]   + b2[r]);
            float e1 = elu_f(h2p[r+1] + c_buf[sid][r+1] + b2[r+1]);
            pk[r/2] = (unsigned int)f2bf(e0) | ((unsigned int)f2bf(e1) << 16);
        }
        unsigned int* hp = reinterpret_cast<unsigned int*>(&h2l[sid][0]);
        #pragma unroll
        for (int w = 0; w < H2 / 2; ++w) hp[w] = pk[w];
    }
    __syncthreads();

    // ---- stage 3: MFMA c-chunks + compile-time-unrolled v accumulation ----
    float v[12];
    #pragma unroll
    for (int q = 0; q < 12; ++q) v[q] = 0.f;

    chunk_body<0>(wid, lane, sid, half, w3b, b3, xr, v, c_buf, h2l);
    chunk_body<1>(wid, lane, sid, half, w3b, b3, xr, v, c_buf, h2l);
    chunk_body<2>(wid, lane, sid, half, w3b, b3, xr, v, c_buf, h2l);
    chunk_body<3>(wid, lane, sid, half, w3b, b3, xr, v, c_buf, h2l);
    chunk_body<4>(wid, lane, sid, half, w3b, b3, xr, v, c_buf, h2l);

    float acc_y = 0.f;
    #pragma unroll
    for (int q = 0; q < 12; ++q) acc_y = fmaf(v[q], v[q], acc_y);

    if (half == 1) yb[sid] = acc_y;
    __syncthreads();
    if (half == 0) y[s] = acc_y + yb[sid];
}

extern "C" void kernel_launch(void* const* d_in, const int* in_sizes, int n_in,
                              void* d_out, int out_size, void* d_ws, size_t ws_size,
                              hipStream_t stream) {
    const float* x  = (const float*)d_in[0];
    const float* W1 = (const float*)d_in[1];
    const float* b1 = (const float*)d_in[2];
    const float* W2 = (const float*)d_in[3];
    const float* b2 = (const float*)d_in[4];
    const float* W3 = (const float*)d_in[5];
    const float* b3 = (const float*)d_in[6];
    float* y = (float*)d_out;
    unsigned short* w3b = (unsigned short*)d_ws;   // 304*32*2 = 19456 B

    const int B = in_sizes[0] / NI;   // 131072, divisible by SPB
    w3cvt<<<dim3((W3R * H2 + 255) / 256), dim3(256), 0, stream>>>(W3, w3b);
    qnet_fused<<<dim3(B / SPB), dim3(256), 0, stream>>>(x, W1, b1, W2, b2, w3b, b3, y, B);
}

// Round 5
// 53.961 us; speedup vs baseline: 4.7051x; 1.4747x over previous
//
#include <hip/hip_runtime.h>
#include <hip/hip_bf16.h>
#include <math.h>

// QuadraticNetCholesky fused kernel, round 5.
// y = x^T (L L^T) x = ||L^T x||^2 ; v_j = sum_{i>=j} x_i * c[i(i+1)/2 + j].
// R5: ALL three matmuls on MFMA (16x16x32 bf16). Stages 1/2 computed as
// D[n][sample] (A=W, B=x/h1) so each lane's 4 C-frag values are consecutive
// n for one sample -> pack -> ds_write_b64 into [sample][n] row-major LDS,
// which is exactly the contiguous-k layout the next stage's frag reads need.
// h1b (34.8KB) unioned with c_buf (33.3KB): live ranges disjoint.

constexpr int NI  = 24;
constexpr int H1  = 128;
constexpr int H2  = 32;
constexpr int SPB = 128;     // samples per block (256 threads, 4 waves)
constexpr int NT_TOT = 19;   // ceil(300/16) W3 row tiles
constexpr int W3R = 304;

typedef __attribute__((ext_vector_type(8))) short bf16x8;
typedef __attribute__((ext_vector_type(4))) float f32x4;

__device__ __forceinline__ float elu_f(float v) {
    return v > 0.0f ? v : __expf(v) - 1.0f;
}
__device__ __forceinline__ float softplus_f(float v) {
    return fmaxf(v, 0.0f) + __logf(1.0f + __expf(-fabsf(v)));
}
__device__ __forceinline__ unsigned short f2bf(float f) {
    return __builtin_bit_cast(unsigned short, __float2bfloat16(f));
}
__device__ __forceinline__ unsigned int pk2(float a, float b) {
    return (unsigned int)f2bf(a) | ((unsigned int)f2bf(b) << 16);
}

// ---- prologue: convert W1/W2/W3 to bf16 tables in d_ws ----
// layout: w1b [128][32] (K padded 24->32, zeros) @0 ; w2b [32][128] @4096 ;
//         w3b [304][32] @8192 (elements, i.e. *2 bytes)
__global__ void wcvt(const float* __restrict__ W1, const float* __restrict__ W2,
                     const float* __restrict__ W3, unsigned short* __restrict__ ws) {
    int idx = blockIdx.x * 256 + threadIdx.x;
    if (idx < 4096) {                        // w1b
        int n = idx >> 5, k = idx & 31;
        ws[idx] = f2bf(k < NI ? W1[n * NI + k] : 0.0f);
    } else if (idx < 8192) {                 // w2b (direct copy, 32x128)
        ws[idx] = f2bf(W2[idx - 4096]);
    } else if (idx < 8192 + W3R * H2) {      // w3b
        int j = idx - 8192;
        int t = j >> 5;
        ws[idx] = f2bf(t < 300 ? W3[j] : 0.0f);
    }
}

// compile-time-pruned v accumulation: only t in [C0, C0+64) emitted
template<int J0, int C0>
__device__ __forceinline__ void vaccum(const float xr[NI], float v[12],
                                       const float* __restrict__ crow) {
    #pragma unroll
    for (int q = 0; q < 12; ++q) {
        const int j = 2 * q + J0;
        #pragma unroll
        for (int i = j; i < NI; ++i) {
            const int t = i * (i + 1) / 2 + j;
            if (t >= C0 && t < C0 + 64)
                v[q] = fmaf(xr[i], crow[t - C0], v[q]);
        }
    }
}

template<int CH>
__device__ __forceinline__ void chunk_body(
    int wid, int lr, int lq, int sid, int half,
    const unsigned short* __restrict__ w3b, const float* __restrict__ b3,
    const float xr[NI], float v[12],
    float (*c_buf)[65], const unsigned short (*h2b)[40])
{
    constexpr int C0 = CH * 64;
    const int nt = CH * 4 + wid;              // wave-uniform N-tile
    if (nt < NT_TOT) {
        const int t = nt * 16 + lr;
        bf16x8 bfrag = *reinterpret_cast<const bf16x8*>(w3b + t * H2 + lq * 8);
        const float bias = b3[t < 300 ? t : 299];
        #pragma unroll
        for (int st = 0; st < SPB / 16; ++st) {
            bf16x8 afrag = *reinterpret_cast<const bf16x8*>(&h2b[st * 16 + lr][lq * 8]);
            f32x4 acc = {0.f, 0.f, 0.f, 0.f};
            acc = __builtin_amdgcn_mfma_f32_16x16x32_bf16(afrag, bfrag, acc, 0, 0, 0);
            #pragma unroll
            for (int r = 0; r < 4; ++r) {
                c_buf[st * 16 + lq * 4 + r][(nt & 3) * 16 + lr] =
                    softplus_f(acc[r] + bias);
            }
        }
    }
    __syncthreads();
    if (half == 0) vaccum<1, C0>(xr, v, c_buf[sid]);   // odd j
    else           vaccum<0, C0>(xr, v, c_buf[sid]);   // even j
    __syncthreads();
}

__global__ __launch_bounds__(256, 3) void qnet_fused(
    const float* __restrict__ x,
    const unsigned short* __restrict__ w1b, const float* __restrict__ b1,
    const unsigned short* __restrict__ w2b, const float* __restrict__ b2,
    const unsigned short* __restrict__ w3b, const float* __restrict__ b3,
    float* __restrict__ y, int B)
{
    // union region: h1b [128][136] bf16 (34816B) then c_buf [128][65] f32 (33280B)
    __shared__ __align__(16) unsigned char uni[SPB * 136 * 2];
    __shared__ __align__(16) unsigned short h2b[SPB][40];   // 10240 B
    __shared__ float yb[SPB];

    auto h1b   = reinterpret_cast<unsigned short(*)[136]>(uni);
    auto c_buf = reinterpret_cast<float(*)[65]>(uni);

    const int tid  = threadIdx.x;
    const int sid  = tid & (SPB - 1);
    const int lane = tid & 63;
    const int lr   = lane & 15, lq = lane >> 4;
    const int half = __builtin_amdgcn_readfirstlane(tid >> 7);
    const int wid  = __builtin_amdgcn_readfirstlane(tid >> 6);
    const size_t sbase = (size_t)blockIdx.x * SPB;

    // ---- x for the final quadratic form stays fp32 in registers ----
    float xr[NI];
    {
        const float4* xp4 = reinterpret_cast<const float4*>(x + (sbase + sid) * NI);
        #pragma unroll
        for (int q = 0; q < NI / 4; ++q) {
            float4 t4 = xp4[q];
            xr[4*q+0] = t4.x; xr[4*q+1] = t4.y; xr[4*q+2] = t4.z; xr[4*q+3] = t4.w;
        }
    }

    // ---- stage 1: h1 = elu(W1 @ x + b1), D[n][sample]; wave w: n-tiles {2w,2w+1}
    #pragma unroll
    for (int u = 0; u < 2; ++u) {
        const int nt1 = 2 * wid + u;
        bf16x8 af = *reinterpret_cast<const bf16x8*>(w1b + (nt1 * 16 + lr) * 32 + lq * 8);
        const float4 bb = *reinterpret_cast<const float4*>(b1 + nt1 * 16 + 4 * lq);
        #pragma unroll
        for (int st = 0; st < 8; ++st) {
            // B-frag: x[sample][k0..k0+7] -> bf16. lq==3 covers K-pad 24..31:
            // w1b is zero there, so values are irrelevant — clamp ptr in-bounds.
            const float* xp = x + (sbase + st * 16 + lr) * NI + (lq == 3 ? 0 : lq * 8);
            float4 x0 = *reinterpret_cast<const float4*>(xp);
            float4 x1 = *reinterpret_cast<const float4*>(xp + 4);
            bf16x8 bf;
            bf[0] = (short)f2bf(x0.x); bf[1] = (short)f2bf(x0.y);
            bf[2] = (short)f2bf(x0.z); bf[3] = (short)f2bf(x0.w);
            bf[4] = (short)f2bf(x1.x); bf[5] = (short)f2bf(x1.y);
            bf[6] = (short)f2bf(x1.z); bf[7] = (short)f2bf(x1.w);
            f32x4 acc = {0.f, 0.f, 0.f, 0.f};
            acc = __builtin_amdgcn_mfma_f32_16x16x32_bf16(af, bf, acc, 0, 0, 0);
            // lane holds h1pre[n = nt1*16+4lq+r][sample = st*16+lr], r=0..3
            unsigned int p0 = pk2(elu_f(acc[0] + bb.x), elu_f(acc[1] + bb.y));
            unsigned int p1 = pk2(elu_f(acc[2] + bb.z), elu_f(acc[3] + bb.w));
            unsigned long long pw = (unsigned long long)p0 | ((unsigned long long)p1 << 32);
            *reinterpret_cast<unsigned long long*>(&h1b[st * 16 + lr][nt1 * 16 + 4 * lq]) = pw;
        }
    }
    __syncthreads();

    // ---- stage 2: h2 = elu(W2 @ h1 + b2), D[n2][sample]; wave w: s-tiles {2w,2w+1}
    #pragma unroll
    for (int u = 0; u < 2; ++u) {
        const int st2 = 2 * wid + u;
        #pragma unroll
        for (int nt2 = 0; nt2 < 2; ++nt2) {
            f32x4 acc = {0.f, 0.f, 0.f, 0.f};
            #pragma unroll
            for (int kk = 0; kk < 4; ++kk) {
                bf16x8 af = *reinterpret_cast<const bf16x8*>(
                    w2b + (nt2 * 16 + lr) * H1 + kk * 32 + lq * 8);
                bf16x8 bf = *reinterpret_cast<const bf16x8*>(
                    &h1b[st2 * 16 + lr][kk * 32 + lq * 8]);
                acc = __builtin_amdgcn_mfma_f32_16x16x32_bf16(af, bf, acc, 0, 0, 0);
            }
            const float4 bb = *reinterpret_cast<const float4*>(b2 + nt2 * 16 + 4 * lq);
            unsigned int p0 = pk2(elu_f(acc[0] + bb.x), elu_f(acc[1] + bb.y));
            unsigned int p1 = pk2(elu_f(acc[2] + bb.z), elu_f(acc[3] + bb.w));
            unsigned long long pw = (unsigned long long)p0 | ((unsigned long long)p1 << 32);
            *reinterpret_cast<unsigned long long*>(&h2b[st2 * 16 + lr][nt2 * 16 + 4 * lq]) = pw;
        }
    }
    __syncthreads();   // h2b ready; h1b dead -> region becomes c_buf

    // ---- stage 3: MFMA c-chunks + compile-time-unrolled v accumulation ----
    float v[12];
    #pragma unroll
    for (int q = 0; q < 12; ++q) v[q] = 0.f;

    chunk_body<0>(wid, lr, lq, sid, half, w3b, b3, xr, v, c_buf, h2b);
    chunk_body<1>(wid, lr, lq, sid, half, w3b, b3, xr, v, c_buf, h2b);
    chunk_body<2>(wid, lr, lq, sid, half, w3b, b3, xr, v, c_buf, h2b);
    chunk_body<3>(wid, lr, lq, sid, half, w3b, b3, xr, v, c_buf, h2b);
    chunk_body<4>(wid, lr, lq, sid, half, w3b, b3, xr, v, c_buf, h2b);

    float acc_y = 0.f;
    #pragma unroll
    for (int q = 0; q < 12; ++q) acc_y = fmaf(v[q], v[q], acc_y);

    if (half == 1) yb[sid] = acc_y;
    __syncthreads();
    if (half == 0) y[sbase + sid] = acc_y + yb[sid];
}

extern "C" void kernel_launch(void* const* d_in, const int* in_sizes, int n_in,
                              void* d_out, int out_size, void* d_ws, size_t ws_size,
                              hipStream_t stream) {
    const float* x  = (const float*)d_in[0];
    const float* W1 = (const float*)d_in[1];
    const float* b1 = (const float*)d_in[2];
    const float* W2 = (const float*)d_in[3];
    const float* b2 = (const float*)d_in[4];
    const float* W3 = (const float*)d_in[5];
    const float* b3 = (const float*)d_in[6];
    float* y = (float*)d_out;

    unsigned short* ws = (unsigned short*)d_ws;      // 35840 B used
    const unsigned short* w1b = ws;
    const unsigned short* w2b = ws + 4096;
    const unsigned short* w3b = ws + 8192;

    const int B = in_sizes[0] / NI;   // 131072, divisible by SPB
    const int cvt_elems = 8192 + W3R * H2;
    wcvt<<<dim3((cvt_elems + 255) / 256), dim3(256), 0, stream>>>(W1, W2, W3, ws);
    qnet_fused<<<dim3(B / SPB), dim3(256), 0, stream>>>(
        x, w1b, b1, w2b, b2, w3b, b3, y, B);
}

// Round 7
// 35.688 us; speedup vs baseline: 7.1142x; 1.5120x over previous
//
#include <hip/hip_runtime.h>
#include <hip/hip_bf16.h>
#include <math.h>

// QuadraticNetCholesky fused kernel, round 7.
// y = x^T (L L^T) x = ||L^T x||^2 ; v_j = sum_{i>=j} x_i * c[i(i+1)/2 + j].
// R7 = R6 with the LDS overflow fixed: layout needs xb(10240)+h1s(10240)+
// h2b(10240) = 30720 B, not 28672 (h2b's last 2048 B were out of bounds ->
// cross-workgroup LDS corruption, nondeterministic absmax 140/488).
// L[30720] -> still 4 blocks/CU (grid 1024 all resident, 16 waves/CU).

constexpr int NI  = 24;
constexpr int H1  = 128;
constexpr int H2  = 32;
constexpr int SPB = 128;     // samples per block (256 threads, 4 waves)
constexpr int NT_TOT = 19;   // ceil(300/16) W3 row tiles
constexpr int W3R = 304;
constexpr float LOG2E = 1.4426950408889634f;
constexpr float LN2SQ = 0.4804530139182014f;   // ln(2)^2

typedef __attribute__((ext_vector_type(8))) short bf16x8;
typedef __attribute__((ext_vector_type(4))) float f32x4;

__device__ __forceinline__ float elu_f(float v) {
    return v > 0.0f ? v : __expf(v) - 1.0f;
}
__device__ __forceinline__ float exp2_hw(float x) {
    float r; asm("v_exp_f32 %0, %1" : "=v"(r) : "v"(x)); return r;
}
__device__ __forceinline__ float log2_hw(float x) {
    float r; asm("v_log_f32 %0, %1" : "=v"(r) : "v"(x)); return r;
}
// softplus(z)/ln2 with z' = z*log2e as input: max(z',0) + log2(1+2^-|z'|)
__device__ __forceinline__ float softplus_g(float zp) {
    return fmaxf(zp, 0.0f) + log2_hw(1.0f + exp2_hw(-fabsf(zp)));
}
__device__ __forceinline__ unsigned short f2bf(float f) {
    return __builtin_bit_cast(unsigned short, __float2bfloat16(f));
}
__device__ __forceinline__ unsigned int pk2(float a, float b) {
    return (unsigned int)f2bf(a) | ((unsigned int)f2bf(b) << 16);
}

// ---- prologue: bf16 weight tables in d_ws ----
// shorts: w1b [128][32] @0 (K-pad 24->32 zeros); w2b [32][128] @4096;
//         w3b [304][32] @8192 (pre-scaled by log2e); b3s f32[304] @short 17920.
__global__ void wcvt(const float* __restrict__ W1, const float* __restrict__ W2,
                     const float* __restrict__ W3, const float* __restrict__ b3,
                     unsigned short* __restrict__ ws) {
    int idx = blockIdx.x * 256 + threadIdx.x;
    if (idx < 4096) {
        int n = idx >> 5, k = idx & 31;
        ws[idx] = f2bf(k < NI ? W1[n * NI + k] : 0.0f);
    } else if (idx < 8192) {
        ws[idx] = f2bf(W2[idx - 4096]);
    } else if (idx < 8192 + W3R * H2) {
        int j = idx - 8192;
        int t = j >> 5;
        ws[idx] = f2bf(t < 300 ? W3[j] * LOG2E : 0.0f);
    } else if (idx < 8192 + W3R * H2 + W3R) {
        int t = idx - (8192 + W3R * H2);
        float* b3s = reinterpret_cast<float*>(ws + 17920);
        b3s[t] = (t < 300) ? b3[t] * LOG2E : 0.0f;
    }
}

// compile-time-pruned v accumulation over window [C0, C0+32)
template<int J0, int C0>
__device__ __forceinline__ void vaccum(const float xr[NI], float v[12],
                                       const float* __restrict__ crow) {
    #pragma unroll
    for (int q = 0; q < 12; ++q) {
        const int j = 2 * q + J0;
        #pragma unroll
        for (int i = j; i < NI; ++i) {
            const int t = i * (i + 1) / 2 + j;
            if (t >= C0 && t < C0 + 32)
                v[q] = fmaf(xr[i], crow[t - C0], v[q]);
        }
    }
}

template<int CH>
__device__ __forceinline__ void chunk_body(
    int w_hi, int w_lo, int lr, int lq, int sid, int half,
    const unsigned short* __restrict__ w3b, const float* __restrict__ b3s,
    const float xr[NI], float v[12],
    float* __restrict__ c_buf, const unsigned short* __restrict__ h2b)
{
    const int my_nt = 2 * CH + w_hi;          // wave-uniform N-tile
    if (my_nt < NT_TOT) {
        const int t = my_nt * 16 + lr;
        bf16x8 wf = *reinterpret_cast<const bf16x8*>(w3b + t * H2 + lq * 8);
        const float bias = b3s[t];
        #pragma unroll
        for (int q = 0; q < 4; ++q) {
            const int st = 4 * w_lo + q;
            bf16x8 hb = *reinterpret_cast<const bf16x8*>(h2b + (st * 16 + lr) * 40 + lq * 8);
            f32x4 a = {0.f, 0.f, 0.f, 0.f};
            a = __builtin_amdgcn_mfma_f32_16x16x32_bf16(hb, wf, a, 0, 0, 0);
            // C: col(lane&15)=t-in-tile, row(4lq+r)=sample-in-st-tile
            #pragma unroll
            for (int r = 0; r < 4; ++r) {
                float g = softplus_g(a[r] + bias);
                c_buf[(st * 16 + 4 * lq + r) * 33 + (my_nt & 1) * 16 + lr] = g;
            }
        }
    }
    __syncthreads();
    if (half == 0) vaccum<1, CH * 32>(xr, v, c_buf + sid * 33);   // odd j
    else           vaccum<0, CH * 32>(xr, v, c_buf + sid * 33);   // even j
    __syncthreads();
}

__global__ __launch_bounds__(256, 4) void qnet_fused(
    const float* __restrict__ x,
    const unsigned short* __restrict__ w1b, const float* __restrict__ b1,
    const unsigned short* __restrict__ w2b, const float* __restrict__ b2,
    const unsigned short* __restrict__ w3b, const float* __restrict__ b3s,
    float* __restrict__ y, int B)
{
    // Layout (bytes): xb [128][40]sh @0..10240 ; h1s [128][40]sh @10240..20480 ;
    // h2b [128][40]sh @20480..30720 ; overlays on dead xb+h1s after stage 2:
    // c_buf [128][33]f32 @0..16896 ; yb f32[128] @16896..17408.
    __shared__ __align__(16) unsigned char L[30720];
    unsigned short* xb  = reinterpret_cast<unsigned short*>(L);          // [128][40]
    unsigned short* h1s = reinterpret_cast<unsigned short*>(L + 10240);  // [128][40]
    unsigned short* h2b = reinterpret_cast<unsigned short*>(L + 20480);  // [128][40]
    float* c_buf = reinterpret_cast<float*>(L);                          // [128][33] overlay
    float* yb    = reinterpret_cast<float*>(L + 16896);                  // [128] overlay

    const int tid  = threadIdx.x;
    const int sid  = tid & (SPB - 1);
    const int lane = tid & 63;
    const int lr   = lane & 15, lq = lane >> 4;
    const int half = __builtin_amdgcn_readfirstlane(tid >> 7);
    const int wid  = __builtin_amdgcn_readfirstlane(tid >> 6);
    const int w_hi = wid >> 1, w_lo = wid & 1;
    const size_t sbase = (size_t)blockIdx.x * SPB;

    // ---- x: fp32 in regs (for quadratic form) + bf16 once into xb ----
    float xr[NI];
    {
        const float4* xp4 = reinterpret_cast<const float4*>(x + (sbase + sid) * NI);
        #pragma unroll
        for (int q = 0; q < NI / 4; ++q) {
            float4 t4 = xp4[q];
            xr[4*q+0] = t4.x; xr[4*q+1] = t4.y; xr[4*q+2] = t4.z; xr[4*q+3] = t4.w;
        }
    }
    if (half == 0) {
        unsigned int pk[12];
        #pragma unroll
        for (int q = 0; q < 12; ++q) pk[q] = pk2(xr[2*q], xr[2*q+1]);
        uint4* dst = reinterpret_cast<uint4*>(xb + sid * 40);
        dst[0] = make_uint4(pk[0], pk[1], pk[2], pk[3]);
        dst[1] = make_uint4(pk[4], pk[5], pk[6], pk[7]);
        dst[2] = make_uint4(pk[8], pk[9], pk[10], pk[11]);
    } else {
        *reinterpret_cast<uint4*>(xb + sid * 40 + 24) = make_uint4(0, 0, 0, 0);  // K-pad
    }
    __syncthreads();

    // ---- stages 1+2, K-chunked by 32 h1-rows; stage-2 partials in regs ----
    f32x4 acc[2][2];
    #pragma unroll
    for (int u = 0; u < 2; ++u)
        #pragma unroll
        for (int n2 = 0; n2 < 2; ++n2) acc[u][n2] = (f32x4){0.f, 0.f, 0.f, 0.f};

    #pragma unroll
    for (int kk = 0; kk < 4; ++kk) {
        // stage 1: h1 rows [32kk, 32kk+32) for all 128 samples
        const int nt1 = 2 * kk + w_hi;
        bf16x8 af = *reinterpret_cast<const bf16x8*>(w1b + (nt1 * 16 + lr) * 32 + lq * 8);
        const float4 bb1 = *reinterpret_cast<const float4*>(b1 + nt1 * 16 + 4 * lq);
        #pragma unroll
        for (int q = 0; q < 4; ++q) {
            const int st = 4 * w_lo + q;
            bf16x8 bf = *reinterpret_cast<const bf16x8*>(xb + (st * 16 + lr) * 40 + lq * 8);
            f32x4 a = {0.f, 0.f, 0.f, 0.f};
            a = __builtin_amdgcn_mfma_f32_16x16x32_bf16(af, bf, a, 0, 0, 0);
            unsigned int p0 = pk2(elu_f(a[0] + bb1.x), elu_f(a[1] + bb1.y));
            unsigned int p1 = pk2(elu_f(a[2] + bb1.z), elu_f(a[3] + bb1.w));
            unsigned long long pw = (unsigned long long)p0 | ((unsigned long long)p1 << 32);
            // sample = st*16+lr; local col = w_hi*16 + 4lq + r
            *reinterpret_cast<unsigned long long*>(
                h1s + (st * 16 + lr) * 40 + w_hi * 16 + 4 * lq) = pw;
        }
        __syncthreads();
        // stage 2: accumulate this K-chunk into register C-tiles
        #pragma unroll
        for (int u = 0; u < 2; ++u) {
            const int st2 = 2 * wid + u;
            bf16x8 hb = *reinterpret_cast<const bf16x8*>(h1s + (st2 * 16 + lr) * 40 + lq * 8);
            #pragma unroll
            for (int n2 = 0; n2 < 2; ++n2) {
                bf16x8 wf = *reinterpret_cast<const bf16x8*>(
                    w2b + (n2 * 16 + lr) * H1 + kk * 32 + lq * 8);
                acc[u][n2] = __builtin_amdgcn_mfma_f32_16x16x32_bf16(wf, hb, acc[u][n2], 0, 0, 0);
            }
        }
        __syncthreads();
    }

    // ---- finish h2: elu + bias, pack bf16 to h2b ----
    #pragma unroll
    for (int u = 0; u < 2; ++u) {
        const int st2 = 2 * wid + u;
        #pragma unroll
        for (int n2 = 0; n2 < 2; ++n2) {
            const float4 bb2 = *reinterpret_cast<const float4*>(b2 + n2 * 16 + 4 * lq);
            unsigned int p0 = pk2(elu_f(acc[u][n2][0] + bb2.x), elu_f(acc[u][n2][1] + bb2.y));
            unsigned int p1 = pk2(elu_f(acc[u][n2][2] + bb2.z), elu_f(acc[u][n2][3] + bb2.w));
            unsigned long long pw = (unsigned long long)p0 | ((unsigned long long)p1 << 32);
            // sample = st2*16+lr; col = n2*16 + 4lq + r
            *reinterpret_cast<unsigned long long*>(
                h2b + (st2 * 16 + lr) * 40 + n2 * 16 + 4 * lq) = pw;
        }
    }
    __syncthreads();   // h2b ready; xb/h1s dead -> region becomes c_buf

    // ---- stage 3: 10 chunks of 32 tril-cols ----
    float v[12];
    #pragma unroll
    for (int q = 0; q < 12; ++q) v[q] = 0.f;

    chunk_body<0>(w_hi, w_lo, lr, lq, sid, half, w3b, b3s, xr, v, c_buf, h2b);
    chunk_body<1>(w_hi, w_lo, lr, lq, sid, half, w3b, b3s, xr, v, c_buf, h2b);
    chunk_body<2>(w_hi, w_lo, lr, lq, sid, half, w3b, b3s, xr, v, c_buf, h2b);
    chunk_body<3>(w_hi, w_lo, lr, lq, sid, half, w3b, b3s, xr, v, c_buf, h2b);
    chunk_body<4>(w_hi, w_lo, lr, lq, sid, half, w3b, b3s, xr, v, c_buf, h2b);
    chunk_body<5>(w_hi, w_lo, lr, lq, sid, half, w3b, b3s, xr, v, c_buf, h2b);
    chunk_body<6>(w_hi, w_lo, lr, lq, sid, half, w3b, b3s, xr, v, c_buf, h2b);
    chunk_body<7>(w_hi, w_lo, lr, lq, sid, half, w3b, b3s, xr, v, c_buf, h2b);
    chunk_body<8>(w_hi, w_lo, lr, lq, sid, half, w3b, b3s, xr, v, c_buf, h2b);
    chunk_body<9>(w_hi, w_lo, lr, lq, sid, half, w3b, b3s, xr, v, c_buf, h2b);

    float acc_y = 0.f;
    #pragma unroll
    for (int q = 0; q < 12; ++q) acc_y = fmaf(v[q], v[q], acc_y);

    if (half == 1) yb[sid] = acc_y;
    __syncthreads();
    if (half == 0) y[sbase + sid] = LN2SQ * (acc_y + yb[sid]);
}

extern "C" void kernel_launch(void* const* d_in, const int* in_sizes, int n_in,
                              void* d_out, int out_size, void* d_ws, size_t ws_size,
                              hipStream_t stream) {
    const float* x  = (const float*)d_in[0];
    const float* W1 = (const float*)d_in[1];
    const float* b1 = (const float*)d_in[2];
    const float* W2 = (const float*)d_in[3];
    const float* b2 = (const float*)d_in[4];
    const float* W3 = (const float*)d_in[5];
    const float* b3 = (const float*)d_in[6];
    float* y = (float*)d_out;

    unsigned short* ws = (unsigned short*)d_ws;      // 37056 B used
    const unsigned short* w1b = ws;
    const unsigned short* w2b = ws + 4096;
    const unsigned short* w3b = ws + 8192;
    const float* b3s = reinterpret_cast<const float*>(ws + 17920);

    const int B = in_sizes[0] / NI;   // 131072, divisible by SPB
    const int cvt_elems = 8192 + W3R * H2 + W3R;
    wcvt<<<dim3((cvt_elems + 255) / 256), dim3(256), 0, stream>>>(W1, W2, W3, b3, ws);
    qnet_fused<<<dim3(B / SPB), dim3(256), 0, stream>>>(
        x, w1b, b1, w2b, b2, w3b, b3s, y, B);
}